// Round 21
// baseline (225.113 us; speedup 1.0000x reference)
//
#include <hip/hip_runtime.h>
#include <hip/hip_bf16.h>
#include <cstdint>

#define N_NODES 50000
#define N_EDGES 800000
#define SCAN_BLOCKS ((N_NODES + 255) / 256)   // 196
#define XSCALE_BLOCKS ((N_NODES * 32 + 255) / 256)  // 6250
#define FILL_BLOCKS ((N_EDGES + 255) / 256)         // 3125

typedef __attribute__((ext_vector_type(8))) short bf16x8;
typedef __attribute__((ext_vector_type(4))) float f32x4;
typedef unsigned int u32;
typedef unsigned short u16;

__device__ __forceinline__ bf16x8 pack_bf16x8(u32 a, u32 b, u32 c, u32 d) {
    union { u32 u[4]; bf16x8 v; } x;
    x.u[0] = a; x.u[1] = b; x.u[2] = c; x.u[3] = d;
    return x.v;
}

__device__ __forceinline__ bf16x8 as_bf16x8(uint4 v) {
    union { uint4 u; bf16x8 b; } x;
    x.u = v;
    return x.b;
}

__device__ __forceinline__ u32 rne_bf16(float x) {
    u32 u = __float_as_uint(x);
    return (u + 0x7FFFu + ((u >> 16) & 1u)) >> 16;
}

// async global->LDS, 16B per lane: lds dest = base + lane*16, g is per-lane.
__device__ __forceinline__ void stage16(const u32* g, u32* lds) {
    __builtin_amdgcn_global_load_lds(
        (const __attribute__((address_space(1))) u32*)g,
        (__attribute__((address_space(3))) u32*)lds, 16, 0, 0);
}

__device__ __forceinline__ int clamp_node(int v) {
    return v < 0 ? 0 : (v >= N_NODES ? N_NODES - 1 : v);
}

// ---------------------------------------------------------------------------
// k_init: blocks [0,196) zero counts; blocks [196,388) do weight prep.
// Weight prep: SINGLE RNE-bf16 fragments; section = 32 KB = 8192 u32;
// frag f = kf*8+nf at section*8192 + f*256; lane l's uint4 at +4l.
// Lane l holds W[k=kf*32+(l>>4)*8+j][n=nf*16+(l&15)].
// Sections: 0,1 = W1 N-halves; 2,3 = W2 K-halves; 4 = fcW1; 5 = fcW2.
// ---------------------------------------------------------------------------

__global__ __launch_bounds__(256) void k_init(int* __restrict__ counts,
                                              const float* __restrict__ W1,
                                              const float* __restrict__ W2,
                                              const float* __restrict__ fcW1,
                                              const float* __restrict__ fcW2,
                                              u32* __restrict__ ftab) {
    if (blockIdx.x < SCAN_BLOCKS) {
        int i = blockIdx.x * 256 + threadIdx.x;
        if (i < N_NODES) counts[i] = 0;
        return;
    }
    int bx = blockIdx.x - SCAN_BLOCKS;    // 0..191
    int l = threadIdx.x;
    if (l >= 64) return;
    int s = bx >> 5, f = bx & 31;
    int kf = f >> 3, nf = f & 7;
    const float* src; int ld, roff, coff;
    switch (s) {
        case 0:  src = W1;   ld = 256; roff = 0;   coff = 0;   break;
        case 1:  src = W1;   ld = 256; roff = 0;   coff = 128; break;
        case 2:  src = W2;   ld = 128; roff = 0;   coff = 0;   break;
        case 3:  src = W2;   ld = 128; roff = 128; coff = 0;   break;
        case 4:  src = fcW1; ld = 128; roff = 0;   coff = 0;   break;
        default: src = fcW2; ld = 128; roff = 0;   coff = 0;   break;
    }
    int col = coff + nf * 16 + (l & 15);
    int krow = roff + kf * 32 + (l >> 4) * 8;
    u32 hp[4];
#pragma unroll
    for (int p = 0; p < 4; ++p) {
        float a0 = src[(size_t)(krow + 2 * p) * ld + col];
        float a1 = src[(size_t)(krow + 2 * p + 1) * ld + col];
        hp[p] = rne_bf16(a0) | (rne_bf16(a1) << 16);
    }
    u32* dst = ftab + (size_t)s * 8192 + (size_t)f * 256;
    *reinterpret_cast<uint4*>(dst + 4 * l) = make_uint4(hp[0], hp[1], hp[2], hp[3]);
}

// 4 edges per thread (uint4 dst load; N_EDGES % 4 == 0)
__global__ void k_count(const int* __restrict__ ei, int* __restrict__ counts) {
    int t = blockIdx.x * blockDim.x + threadIdx.x;
    if (t < N_EDGES / 4) {
        int4 d = reinterpret_cast<const int4*>(ei + N_EDGES)[t];
        atomicAdd(&counts[clamp_node(d.x)], 1);
        atomicAdd(&counts[clamp_node(d.y)], 1);
        atomicAdd(&counts[clamp_node(d.z)], 1);
        atomicAdd(&counts[clamp_node(d.w)], 1);
    }
}

__global__ __launch_bounds__(256) void k_scan1(const int* __restrict__ counts,
                                               int* __restrict__ part,
                                               int* __restrict__ bsum) {
    __shared__ int s[256];
    const int tid = threadIdx.x;
    const int i = blockIdx.x * 256 + tid;
    int v = (i < N_NODES) ? counts[i] : 0;
    s[tid] = v;
    __syncthreads();
    for (int off = 1; off < 256; off <<= 1) {
        int t = (tid >= off) ? s[tid - off] : 0;
        __syncthreads();
        s[tid] += t;
        __syncthreads();
    }
    if (i < N_NODES) part[i] = s[tid];
    if (tid == 255) bsum[blockIdx.x] = s[255];
}

__global__ __launch_bounds__(256) void k_scan2(const int* __restrict__ bsum,
                                               int* __restrict__ boff) {
    __shared__ int s[256];
    const int tid = threadIdx.x;
    int v = (tid < SCAN_BLOCKS) ? bsum[tid] : 0;
    s[tid] = v;
    __syncthreads();
    for (int off = 1; off < 256; off <<= 1) {
        int t = (tid >= off) ? s[tid - off] : 0;
        __syncthreads();
        s[tid] += t;
        __syncthreads();
    }
    if (tid < SCAN_BLOCKS) boff[tid] = s[tid] - v;
}

// scan3 also emits cursor (=offsets copy for fill) and dinv (from counts)
__global__ __launch_bounds__(256) void k_scan3(const int* __restrict__ part,
                                               const int* __restrict__ counts,
                                               const int* __restrict__ boff,
                                               int* __restrict__ offsets,
                                               int* __restrict__ cursor,
                                               float* __restrict__ dinv) {
    const int i = blockIdx.x * 256 + threadIdx.x;
    if (i < N_NODES) {
        int off = part[i] - counts[i] + boff[blockIdx.x];
        offsets[i] = off;
        cursor[i]  = off;
        dinv[i]    = rsqrtf((float)counts[i] + 1.0f);
    }
    if (i == 0) offsets[N_NODES] = N_EDGES;
}

// ---------------------------------------------------------------------------
// k_xf: blocks [0,6250) xscale; blocks [6250,9375) fill.
// Both depend only on scan3 outputs; co-scheduling hides xscale (streaming)
// under fill (scatter-bound, VALU-idle).
// ---------------------------------------------------------------------------

__global__ __launch_bounds__(256) void k_xf(const float* __restrict__ x,
                                            const float* __restrict__ dinv,
                                            u32* __restrict__ xs,
                                            const int* __restrict__ ei,
                                            int* __restrict__ cursor,
                                            u16* __restrict__ csr) {
    if (blockIdx.x < XSCALE_BLOCKS) {
        int idx = blockIdx.x * 256 + threadIdx.x;
        if (idx < N_NODES * 32) {
            int node = idx >> 5;
            float di = dinv[node];
            float4 v = reinterpret_cast<const float4*>(x)[idx];
            u32 w0 = rne_bf16(v.x * di) | (rne_bf16(v.y * di) << 16);
            u32 w1 = rne_bf16(v.z * di) | (rne_bf16(v.w * di) << 16);
            reinterpret_cast<uint2*>(xs)[idx] = make_uint2(w0, w1);
        }
    } else {
        int e = (blockIdx.x - XSCALE_BLOCKS) * 256 + threadIdx.x;
        if (e < N_EDGES) {
            int src = clamp_node(ei[e]);
            int dst = clamp_node(ei[N_EDGES + e]);
            int slot = atomicAdd(&cursor[dst], 1);
            if (slot >= 0 && slot < N_EDGES) csr[slot] = (u16)src;
        }
    }
}

// ---------------------------------------------------------------------------
// Propagation over pre-scaled bf16 features; csr u16; plain f32 stores.
// ---------------------------------------------------------------------------

template <bool HAS_BIAS, bool RELU>
__global__ __launch_bounds__(256) void k_prop(const u32* __restrict__ xs,
                                              float* __restrict__ out,
                                              const float* __restrict__ dinv,
                                              const int* __restrict__ offsets,
                                              const u16* __restrict__ csr,
                                              const float* __restrict__ bias) {
    const int wave = threadIdx.x >> 6;
    const int lane = threadIdx.x & 63;
    const int half = lane >> 5;
    const int lc   = lane & 31;          // 4-channel group
    const int node = (blockIdx.x * 4 + wave) * 2 + half;
    if (node >= N_NODES) return;

    const uint2* __restrict__ xp = reinterpret_cast<const uint2*>(xs);
    const float di = dinv[node];

    uint2 sv = xp[(size_t)node * 32 + lc];
    float ax = __uint_as_float(sv.x << 16);
    float ay = __uint_as_float(sv.x & 0xFFFF0000u);
    float az = __uint_as_float(sv.y << 16);
    float aw = __uint_as_float(sv.y & 0xFFFF0000u);

    int e = offsets[node];
    const int eend = offsets[node + 1];
    for (; e + 4 <= eend; e += 4) {
        int s0 = csr[e + 0], s1 = csr[e + 1], s2 = csr[e + 2], s3 = csr[e + 3];
        uint2 v0 = xp[(size_t)s0 * 32 + lc];
        uint2 v1 = xp[(size_t)s1 * 32 + lc];
        uint2 v2 = xp[(size_t)s2 * 32 + lc];
        uint2 v3 = xp[(size_t)s3 * 32 + lc];
        ax += __uint_as_float(v0.x << 16);
        ay += __uint_as_float(v0.x & 0xFFFF0000u);
        az += __uint_as_float(v0.y << 16);
        aw += __uint_as_float(v0.y & 0xFFFF0000u);
        ax += __uint_as_float(v1.x << 16);
        ay += __uint_as_float(v1.x & 0xFFFF0000u);
        az += __uint_as_float(v1.y << 16);
        aw += __uint_as_float(v1.y & 0xFFFF0000u);
        ax += __uint_as_float(v2.x << 16);
        ay += __uint_as_float(v2.x & 0xFFFF0000u);
        az += __uint_as_float(v2.y << 16);
        aw += __uint_as_float(v2.y & 0xFFFF0000u);
        ax += __uint_as_float(v3.x << 16);
        ay += __uint_as_float(v3.x & 0xFFFF0000u);
        az += __uint_as_float(v3.y << 16);
        aw += __uint_as_float(v3.y & 0xFFFF0000u);
    }
    for (; e < eend; ++e) {
        int s = csr[e];
        uint2 v = xp[(size_t)s * 32 + lc];
        ax += __uint_as_float(v.x << 16);
        ay += __uint_as_float(v.x & 0xFFFF0000u);
        az += __uint_as_float(v.y << 16);
        aw += __uint_as_float(v.y & 0xFFFF0000u);
    }

    float4 o;
    o.x = di * ax; o.y = di * ay; o.z = di * az; o.w = di * aw;
    if (HAS_BIAS) {
        float4 bb = reinterpret_cast<const float4*>(bias)[lc];
        o.x += bb.x; o.y += bb.y; o.z += bb.z; o.w += bb.w;
    }
    if (RELU) {
        o.x = fmaxf(o.x, 0.0f); o.y = fmaxf(o.y, 0.0f);
        o.z = fmaxf(o.z, 0.0f); o.w = fmaxf(o.w, 0.0f);
    }
    reinterpret_cast<float4*>(out)[(size_t)node * 32 + lc] = o;
}

// ---------------------------------------------------------------------------
// Fused 2-GEMM chain, 2-PRODUCT scheme (r17/r20): W is RNE-bf16 (single
// frag), A split hi/lo so w*ahi + w*alo = w*a exactly. 32 KB section
// LDS-resident per phase, pure-LDS inner loops, 64-row blocks, grid 782.
// ---------------------------------------------------------------------------

template <int NHALF, int ACT1, bool FINAL_BIAS, bool BF16_OUT>
__global__ __launch_bounds__(256, 3) void k_fused(
        const float* __restrict__ A,
        const u32* __restrict__ ftabW1,
        const u32* __restrict__ ftabW2,
        const float* __restrict__ b1v,
        const float* __restrict__ b2v,
        float* __restrict__ C,
        u32* __restrict__ C16,
        const float* __restrict__ dscale,
        int M) {
    __shared__ u32 lds_w[8192];   // 32 KB: one phase's weight section

    const int tid = threadIdx.x;
    const int wave = tid >> 6, l = tid & 63;
    const int l15 = l & 15, l4 = l >> 4;
    const int r = blockIdx.x * 64 + wave * 16 + l15;
    const float* arow = A + (size_t)(r < M ? r : M - 1) * 128;

    auto stage_sec = [&](const u32* sec) {
#pragma unroll
        for (int i = 0; i < 8; ++i) {
            int off = (i * 4 + wave) * 256;
            stage16(sec + off + 4 * l, lds_w + off);
        }
    };

    // A fragments loaded/split ONCE
    bf16x8 ahi[4], alo[4];
#pragma unroll
    for (int kf = 0; kf < 4; ++kf) {
        const float* ap = arow + kf * 32 + l4 * 8;
        float4 v0 = *reinterpret_cast<const float4*>(ap);
        float4 v1 = *reinterpret_cast<const float4*>(ap + 4);
        float av[8] = {v0.x, v0.y, v0.z, v0.w, v1.x, v1.y, v1.z, v1.w};
        u32 hp[4], lp[4];
#pragma unroll
        for (int p = 0; p < 4; ++p) {
            float a0 = av[2 * p], a1 = av[2 * p + 1];
            u32 h0 = __float_as_uint(a0) & 0xFFFF0000u;
            u32 h1 = __float_as_uint(a1) & 0xFFFF0000u;
            float q0 = a0 - __uint_as_float(h0);
            float q1 = a1 - __uint_as_float(h1);
            hp[p] = (h0 >> 16) | h1;
            lp[p] = ((__float_as_uint(q0) & 0xFFFF0000u) >> 16) |
                    (__float_as_uint(q1) & 0xFFFF0000u);
        }
        ahi[kf] = pack_bf16x8(hp[0], hp[1], hp[2], hp[3]);
        alo[kf] = pack_bf16x8(lp[0], lp[1], lp[2], lp[3]);
    }

    f32x4 accQ[8] = {};

    stage_sec(ftabW1);   // W1 half 0
    __syncthreads();

    for (int half = 0; half < NHALF; ++half) {
        // ---------------- phase 1: accH = W1h^T · A^T ----------------
        f32x4 accH[8] = {};
#pragma unroll
        for (int kf = 0; kf < 4; ++kf) {
            uint4 wh[8];
#pragma unroll
            for (int nf = 0; nf < 8; ++nf)
                wh[nf] = *reinterpret_cast<const uint4*>(
                    lds_w + (kf * 8 + nf) * 256 + 4 * l);
            __builtin_amdgcn_sched_group_barrier(0x100, 8, 0);   // 8 DS_READ
#pragma unroll
            for (int nf = 0; nf < 8; ++nf) {
                bf16x8 whi = as_bf16x8(wh[nf]);
                accH[nf] = __builtin_amdgcn_mfma_f32_16x16x32_bf16(whi, ahi[kf], accH[nf], 0, 0, 0);
                accH[nf] = __builtin_amdgcn_mfma_f32_16x16x32_bf16(whi, alo[kf], accH[nf], 0, 0, 0);
            }
            __builtin_amdgcn_sched_group_barrier(0x8, 16, 0);    // 16 MFMA
        }
        __syncthreads();                           // done reading W1h
        stage_sec(ftabW2 + (size_t)half * 8192);   // async stage W2h

        // ---- epilogue 1 (VALU, overlaps staging): bias+act, split-pack ----
        u32 hpk[8][4];
#pragma unroll
        for (int nf = 0; nf < 8; ++nf) {
            const float4 bb = *reinterpret_cast<const float4*>(
                b1v + half * 128 + nf * 16 + l4 * 4);
            const float bbv[4] = {bb.x, bb.y, bb.z, bb.w};
#pragma unroll
            for (int reg = 0; reg < 4; ++reg) {
                float v = accH[nf][reg] + bbv[reg];
                if (ACT1 == 1) v = fmaxf(v, 0.0f);
                else           v = v > 0.0f ? v : (expf(v) - 1.0f);
                u32 vh = __float_as_uint(v) & 0xFFFF0000u;
                float rr = v - __uint_as_float(vh);
                hpk[nf][reg] = (vh >> 16) | (__float_as_uint(rr) & 0xFFFF0000u);
            }
        }
        __syncthreads();                           // W2h staged & visible

        // ---------------- phase 2: accQ += W2h^T · H^T ----------------
#pragma unroll
        for (int kf = 0; kf < 4; ++kf) {
            uint4 wh[8];
#pragma unroll
            for (int nf = 0; nf < 8; ++nf)
                wh[nf] = *reinterpret_cast<const uint4*>(
                    lds_w + (kf * 8 + nf) * 256 + 4 * l);
            __builtin_amdgcn_sched_group_barrier(0x100, 8, 0);   // 8 DS_READ

            u32 got[8];
#pragma unroll
            for (int je = 0; je < 8; ++je) {
                int srcLane = ((l4 & 1) * 2 + (je >> 2)) * 16 + l15;
                u32 g0 = __shfl(hpk[2 * kf][je & 3], srcLane, 64);
                u32 g1 = __shfl(hpk[2 * kf + 1][je & 3], srcLane, 64);
                got[je] = (l4 & 2) ? g1 : g0;
            }
            u32 hh[4], gg[4];
#pragma unroll
            for (int p = 0; p < 4; ++p) {
                hh[p] = (got[2 * p] & 0xFFFFu) | (got[2 * p + 1] << 16);
                gg[p] = (got[2 * p] >> 16) | (got[2 * p + 1] & 0xFFFF0000u);
            }
            bf16x8 bh = pack_bf16x8(hh[0], hh[1], hh[2], hh[3]);
            bf16x8 bl = pack_bf16x8(gg[0], gg[1], gg[2], gg[3]);

#pragma unroll
            for (int nf = 0; nf < 8; ++nf) {
                bf16x8 whi = as_bf16x8(wh[nf]);
                accQ[nf] = __builtin_amdgcn_mfma_f32_16x16x32_bf16(whi, bh, accQ[nf], 0, 0, 0);
                accQ[nf] = __builtin_amdgcn_mfma_f32_16x16x32_bf16(whi, bl, accQ[nf], 0, 0, 0);
            }
            __builtin_amdgcn_sched_group_barrier(0x8, 16, 0);    // 16 MFMA
        }

        if (half + 1 < NHALF) {
            __syncthreads();
            stage_sec(ftabW1 + (size_t)(half + 1) * 8192);
            __syncthreads();
        }
    }

    // ---- final epilogue ----
    if (r < M) {
        if (BF16_OUT) {
            float sc = dscale[r];
#pragma unroll
            for (int nf = 0; nf < 8; ++nf) {
                u32 w0 = rne_bf16(accQ[nf][0] * sc) | (rne_bf16(accQ[nf][1] * sc) << 16);
                u32 w1 = rne_bf16(accQ[nf][2] * sc) | (rne_bf16(accQ[nf][3] * sc) << 16);
                reinterpret_cast<uint2*>(C16)[(size_t)r * 32 + nf * 4 + l4] =
                    make_uint2(w0, w1);
            }
        } else {
#pragma unroll
            for (int nf = 0; nf < 8; ++nf) {
                float4 v;
                v.x = accQ[nf][0]; v.y = accQ[nf][1];
                v.z = accQ[nf][2]; v.w = accQ[nf][3];
                if (FINAL_BIAS) {
                    const float4 bb = *reinterpret_cast<const float4*>(b2v + nf * 16 + l4 * 4);
                    v.x += bb.x; v.y += bb.y; v.z += bb.z; v.w += bb.w;
                }
                *reinterpret_cast<float4*>(C + (size_t)r * 128 + nf * 16 + l4 * 4) = v;
            }
        }
    }
}

// ---------------------------------------------------------------------------
// launch
// ---------------------------------------------------------------------------

extern "C" void kernel_launch(void* const* d_in, const int* in_sizes, int n_in,
                              void* d_out, int out_size, void* d_ws, size_t ws_size,
                              hipStream_t stream) {
    const float* x    = (const float*)d_in[0];
    const int*   ei   = (const int*)d_in[1];   // int64 in reference -> int32 from harness
    const float* W1   = (const float*)d_in[2]; // [128,256]
    const float* b1   = (const float*)d_in[3];
    const float* W2   = (const float*)d_in[4]; // [256,128]
    const float* b2   = (const float*)d_in[5];
    const float* fcW1 = (const float*)d_in[6]; // [128,128]
    const float* fcb1 = (const float*)d_in[7];
    const float* fcW2 = (const float*)d_in[8]; // [128,128]
    const float* fcb2 = (const float*)d_in[9];
    float* out        = (float*)d_out;         // [N,128], also ping-pong scratch

    char* ws = (char*)d_ws;
    size_t off = 0;
    auto alloc = [&](size_t bytes) {
        void* p = ws + off;
        off += (bytes + 255) & ~(size_t)255;
        return p;
    };
    int*   counts  = (int*)alloc(N_NODES * sizeof(int));
    int*   cursor  = (int*)alloc(N_NODES * sizeof(int));
    int*   part    = (int*)alloc(N_NODES * sizeof(int));
    int*   bsum    = (int*)alloc(SCAN_BLOCKS * sizeof(int));
    int*   boff    = (int*)alloc(SCAN_BLOCKS * sizeof(int));
    int*   offsets = (int*)alloc((N_NODES + 1) * sizeof(int));
    u16*   csr     = (u16*)alloc(N_EDGES * sizeof(u16));
    float* dinv    = (float*)alloc(N_NODES * sizeof(float));
    u32*   ftab    = (u32*)alloc((size_t)6 * 8192 * sizeof(u32));
    u32*   xs      = (u32*)alloc((size_t)N_NODES * 128 * 2);   // bf16 features
    u32*   qs      = (u32*)alloc((size_t)N_NODES * 128 * 2);   // bf16 mid output
    (void)ws_size; (void)n_in; (void)in_sizes; (void)out_size;

    const u32 SEC = 8192;  // u32 per 32 KB section

    // graph preprocessing + weight prep (merged launches)
    k_init<<<SCAN_BLOCKS + 192, 256, 0, stream>>>(counts, W1, W2, fcW1, fcW2, ftab);
    k_count<<<(N_EDGES / 4 + 255) / 256, 256, 0, stream>>>(ei, counts);
    k_scan1<<<SCAN_BLOCKS, 256, 0, stream>>>(counts, part, bsum);
    k_scan2<<<1, 256, 0, stream>>>(bsum, boff);
    k_scan3<<<SCAN_BLOCKS, 256, 0, stream>>>(part, counts, boff, offsets, cursor, dinv);
    k_xf<<<XSCALE_BLOCKS + FILL_BLOCKS, 256, 0, stream>>>(x, dinv, xs, ei, cursor, csr);

    const int prop_grid = (N_NODES + 7) / 8;  // 6250: 8 nodes/block, 2 per wave
    const int gm = (N_NODES + 63) / 64;       // 782 (64 rows/block, 16 per wave)

    // layer 1 propagate: agg = dinv*(sum xs + xs_self) -> out (f32 scratch)
    k_prop<false, false><<<prop_grid, 256, 0, stream>>>(xs, out, dinv, offsets, csr, nullptr);

    // fused mid: qs = bf16( dinv * (relu(agg@W1 + b1) @ W2) )
    k_fused<2, 1, false, true><<<gm, 256, 0, stream>>>(out, ftab, ftab + 2 * SEC,
                                                       b1, nullptr, nullptr, qs, dinv, N_NODES);

    // layer 2 propagate: z = relu( dinv*(sum qs + qs_self) + b2 ) -> out
    k_prop<true, true><<<prop_grid, 256, 0, stream>>>(qs, out, dinv, offsets, csr, b2);

    // fused head (in-place): out = elu(out@fcW1 + fcb1) @ fcW2 + fcb2
    k_fused<1, 2, true, false><<<gm, 256, 0, stream>>>(out, ftab + 4 * SEC, ftab + 5 * SEC,
                                                       fcb1, fcb2, out, nullptr, nullptr, N_NODES);
}

// Round 22
// 215.509 us; speedup vs baseline: 1.0446x; 1.0446x over previous
//
#include <hip/hip_runtime.h>
#include <hip/hip_bf16.h>
#include <cstdint>

#define N_NODES 50000
#define N_EDGES 800000
#define SCAN_BLOCKS ((N_NODES + 255) / 256)   // 196

typedef __attribute__((ext_vector_type(8))) short bf16x8;
typedef __attribute__((ext_vector_type(4))) float f32x4;
typedef unsigned int u32;
typedef unsigned short u16;

__device__ __forceinline__ bf16x8 pack_bf16x8(u32 a, u32 b, u32 c, u32 d) {
    union { u32 u[4]; bf16x8 v; } x;
    x.u[0] = a; x.u[1] = b; x.u[2] = c; x.u[3] = d;
    return x.v;
}

__device__ __forceinline__ bf16x8 as_bf16x8(uint4 v) {
    union { uint4 u; bf16x8 b; } x;
    x.u = v;
    return x.b;
}

__device__ __forceinline__ u32 rne_bf16(float x) {
    u32 u = __float_as_uint(x);
    return (u + 0x7FFFu + ((u >> 16) & 1u)) >> 16;
}

// async global->LDS, 16B per lane: lds dest = base + lane*16, g is per-lane.
__device__ __forceinline__ void stage16(const u32* g, u32* lds) {
    __builtin_amdgcn_global_load_lds(
        (const __attribute__((address_space(1))) u32*)g,
        (__attribute__((address_space(3))) u32*)lds, 16, 0, 0);
}

__device__ __forceinline__ int clamp_node(int v) {
    return v < 0 ? 0 : (v >= N_NODES ? N_NODES - 1 : v);
}

// ---------------------------------------------------------------------------
// k_init: blocks [0,196) zero counts; blocks [196,388) do weight prep.
// Weight prep: SINGLE RNE-bf16 fragments; section = 32 KB = 8192 u32;
// frag f = kf*8+nf at section*8192 + f*256; lane l's uint4 at +4l.
// Lane l holds W[k=kf*32+(l>>4)*8+j][n=nf*16+(l&15)].
// Sections: 0,1 = W1 N-halves; 2,3 = W2 K-halves; 4 = fcW1; 5 = fcW2.
// ---------------------------------------------------------------------------

__global__ __launch_bounds__(256) void k_init(int* __restrict__ counts,
                                              const float* __restrict__ W1,
                                              const float* __restrict__ W2,
                                              const float* __restrict__ fcW1,
                                              const float* __restrict__ fcW2,
                                              u32* __restrict__ ftab) {
    if (blockIdx.x < SCAN_BLOCKS) {
        int i = blockIdx.x * 256 + threadIdx.x;
        if (i < N_NODES) counts[i] = 0;
        return;
    }
    int bx = blockIdx.x - SCAN_BLOCKS;    // 0..191
    int l = threadIdx.x;
    if (l >= 64) return;
    int s = bx >> 5, f = bx & 31;
    int kf = f >> 3, nf = f & 7;
    const float* src; int ld, roff, coff;
    switch (s) {
        case 0:  src = W1;   ld = 256; roff = 0;   coff = 0;   break;
        case 1:  src = W1;   ld = 256; roff = 0;   coff = 128; break;
        case 2:  src = W2;   ld = 128; roff = 0;   coff = 0;   break;
        case 3:  src = W2;   ld = 128; roff = 128; coff = 0;   break;
        case 4:  src = fcW1; ld = 128; roff = 0;   coff = 0;   break;
        default: src = fcW2; ld = 128; roff = 0;   coff = 0;   break;
    }
    int col = coff + nf * 16 + (l & 15);
    int krow = roff + kf * 32 + (l >> 4) * 8;
    u32 hp[4];
#pragma unroll
    for (int p = 0; p < 4; ++p) {
        float a0 = src[(size_t)(krow + 2 * p) * ld + col];
        float a1 = src[(size_t)(krow + 2 * p + 1) * ld + col];
        hp[p] = rne_bf16(a0) | (rne_bf16(a1) << 16);
    }
    u32* dst = ftab + (size_t)s * 8192 + (size_t)f * 256;
    *reinterpret_cast<uint4*>(dst + 4 * l) = make_uint4(hp[0], hp[1], hp[2], hp[3]);
}

// 4 edges per thread (uint4 dst load; N_EDGES % 4 == 0)
__global__ void k_count(const int* __restrict__ ei, int* __restrict__ counts) {
    int t = blockIdx.x * blockDim.x + threadIdx.x;
    if (t < N_EDGES / 4) {
        int4 d = reinterpret_cast<const int4*>(ei + N_EDGES)[t];
        atomicAdd(&counts[clamp_node(d.x)], 1);
        atomicAdd(&counts[clamp_node(d.y)], 1);
        atomicAdd(&counts[clamp_node(d.z)], 1);
        atomicAdd(&counts[clamp_node(d.w)], 1);
    }
}

// xs[i][c] = bf16_rne( dinv[i] * x[i][c] )
__global__ __launch_bounds__(256) void k_xscale(const float* __restrict__ x,
                                                const float* __restrict__ dinv,
                                                u32* __restrict__ xs) {
    int idx = blockIdx.x * 256 + threadIdx.x;      // one float4 group
    if (idx < N_NODES * 32) {
        int node = idx >> 5;
        float di = dinv[node];
        float4 v = reinterpret_cast<const float4*>(x)[idx];
        u32 w0 = rne_bf16(v.x * di) | (rne_bf16(v.y * di) << 16);
        u32 w1 = rne_bf16(v.z * di) | (rne_bf16(v.w * di) << 16);
        reinterpret_cast<uint2*>(xs)[idx] = make_uint2(w0, w1);
    }
}

__global__ __launch_bounds__(256) void k_scan1(const int* __restrict__ counts,
                                               int* __restrict__ part,
                                               int* __restrict__ bsum) {
    __shared__ int s[256];
    const int tid = threadIdx.x;
    const int i = blockIdx.x * 256 + tid;
    int v = (i < N_NODES) ? counts[i] : 0;
    s[tid] = v;
    __syncthreads();
    for (int off = 1; off < 256; off <<= 1) {
        int t = (tid >= off) ? s[tid - off] : 0;
        __syncthreads();
        s[tid] += t;
        __syncthreads();
    }
    if (i < N_NODES) part[i] = s[tid];
    if (tid == 255) bsum[blockIdx.x] = s[255];
}

__global__ __launch_bounds__(256) void k_scan2(const int* __restrict__ bsum,
                                               int* __restrict__ boff) {
    __shared__ int s[256];
    const int tid = threadIdx.x;
    int v = (tid < SCAN_BLOCKS) ? bsum[tid] : 0;
    s[tid] = v;
    __syncthreads();
    for (int off = 1; off < 256; off <<= 1) {
        int t = (tid >= off) ? s[tid - off] : 0;
        __syncthreads();
        s[tid] += t;
        __syncthreads();
    }
    if (tid < SCAN_BLOCKS) boff[tid] = s[tid] - v;
}

// scan3 also emits cursor (=offsets copy for k_fill) and dinv (from counts)
__global__ __launch_bounds__(256) void k_scan3(const int* __restrict__ part,
                                               const int* __restrict__ counts,
                                               const int* __restrict__ boff,
                                               int* __restrict__ offsets,
                                               int* __restrict__ cursor,
                                               float* __restrict__ dinv) {
    const int i = blockIdx.x * 256 + threadIdx.x;
    if (i < N_NODES) {
        int off = part[i] - counts[i] + boff[blockIdx.x];
        offsets[i] = off;
        cursor[i]  = off;
        dinv[i]    = rsqrtf((float)counts[i] + 1.0f);
    }
    if (i == 0) offsets[N_NODES] = N_EDGES;
}

// cursor pre-filled with offsets; csr u16; plain stores.
__global__ void k_fill(const int* __restrict__ ei, int* __restrict__ cursor,
                       u16* __restrict__ csr) {
    int e = blockIdx.x * blockDim.x + threadIdx.x;
    if (e < N_EDGES) {
        int src = clamp_node(ei[e]);
        int dst = clamp_node(ei[N_EDGES + e]);
        int slot = atomicAdd(&cursor[dst], 1);
        if (slot >= 0 && slot < N_EDGES) csr[slot] = (u16)src;
    }
}

// ---------------------------------------------------------------------------
// Propagation over pre-scaled bf16 features; csr u16; plain f32 stores.
// ---------------------------------------------------------------------------

template <bool HAS_BIAS, bool RELU>
__global__ __launch_bounds__(256) void k_prop(const u32* __restrict__ xs,
                                              float* __restrict__ out,
                                              const float* __restrict__ dinv,
                                              const int* __restrict__ offsets,
                                              const u16* __restrict__ csr,
                                              const float* __restrict__ bias) {
    const int wave = threadIdx.x >> 6;
    const int lane = threadIdx.x & 63;
    const int half = lane >> 5;
    const int lc   = lane & 31;          // 4-channel group
    const int node = (blockIdx.x * 4 + wave) * 2 + half;
    if (node >= N_NODES) return;

    const uint2* __restrict__ xp = reinterpret_cast<const uint2*>(xs);
    const float di = dinv[node];

    uint2 sv = xp[(size_t)node * 32 + lc];
    float ax = __uint_as_float(sv.x << 16);
    float ay = __uint_as_float(sv.x & 0xFFFF0000u);
    float az = __uint_as_float(sv.y << 16);
    float aw = __uint_as_float(sv.y & 0xFFFF0000u);

    int e = offsets[node];
    const int eend = offsets[node + 1];
    for (; e + 4 <= eend; e += 4) {
        int s0 = csr[e + 0], s1 = csr[e + 1], s2 = csr[e + 2], s3 = csr[e + 3];
        uint2 v0 = xp[(size_t)s0 * 32 + lc];
        uint2 v1 = xp[(size_t)s1 * 32 + lc];
        uint2 v2 = xp[(size_t)s2 * 32 + lc];
        uint2 v3 = xp[(size_t)s3 * 32 + lc];
        ax += __uint_as_float(v0.x << 16);
        ay += __uint_as_float(v0.x & 0xFFFF0000u);
        az += __uint_as_float(v0.y << 16);
        aw += __uint_as_float(v0.y & 0xFFFF0000u);
        ax += __uint_as_float(v1.x << 16);
        ay += __uint_as_float(v1.x & 0xFFFF0000u);
        az += __uint_as_float(v1.y << 16);
        aw += __uint_as_float(v1.y & 0xFFFF0000u);
        ax += __uint_as_float(v2.x << 16);
        ay += __uint_as_float(v2.x & 0xFFFF0000u);
        az += __uint_as_float(v2.y << 16);
        aw += __uint_as_float(v2.y & 0xFFFF0000u);
        ax += __uint_as_float(v3.x << 16);
        ay += __uint_as_float(v3.x & 0xFFFF0000u);
        az += __uint_as_float(v3.y << 16);
        aw += __uint_as_float(v3.y & 0xFFFF0000u);
    }
    for (; e < eend; ++e) {
        int s = csr[e];
        uint2 v = xp[(size_t)s * 32 + lc];
        ax += __uint_as_float(v.x << 16);
        ay += __uint_as_float(v.x & 0xFFFF0000u);
        az += __uint_as_float(v.y << 16);
        aw += __uint_as_float(v.y & 0xFFFF0000u);
    }

    float4 o;
    o.x = di * ax; o.y = di * ay; o.z = di * az; o.w = di * aw;
    if (HAS_BIAS) {
        float4 bb = reinterpret_cast<const float4*>(bias)[lc];
        o.x += bb.x; o.y += bb.y; o.z += bb.z; o.w += bb.w;
    }
    if (RELU) {
        o.x = fmaxf(o.x, 0.0f); o.y = fmaxf(o.y, 0.0f);
        o.z = fmaxf(o.z, 0.0f); o.w = fmaxf(o.w, 0.0f);
    }
    reinterpret_cast<float4*>(out)[(size_t)node * 32 + lc] = o;
}

// ---------------------------------------------------------------------------
// Fused 2-GEMM chain, 2-PRODUCT scheme (r17/r20): W is RNE-bf16 (single
// frag), A split hi/lo so w*ahi + w*alo = w*a exactly. 32 KB section
// LDS-resident per phase, pure-LDS inner loops, 64-row blocks, grid 782.
// ---------------------------------------------------------------------------

template <int NHALF, int ACT1, bool FINAL_BIAS, bool BF16_OUT>
__global__ __launch_bounds__(256, 3) void k_fused(
        const float* __restrict__ A,
        const u32* __restrict__ ftabW1,
        const u32* __restrict__ ftabW2,
        const float* __restrict__ b1v,
        const float* __restrict__ b2v,
        float* __restrict__ C,
        u32* __restrict__ C16,
        const float* __restrict__ dscale,
        int M) {
    __shared__ u32 lds_w[8192];   // 32 KB: one phase's weight section

    const int tid = threadIdx.x;
    const int wave = tid >> 6, l = tid & 63;
    const int l15 = l & 15, l4 = l >> 4;
    const int r = blockIdx.x * 64 + wave * 16 + l15;
    const float* arow = A + (size_t)(r < M ? r : M - 1) * 128;

    auto stage_sec = [&](const u32* sec) {
#pragma unroll
        for (int i = 0; i < 8; ++i) {
            int off = (i * 4 + wave) * 256;
            stage16(sec + off + 4 * l, lds_w + off);
        }
    };

    // A fragments loaded/split ONCE
    bf16x8 ahi[4], alo[4];
#pragma unroll
    for (int kf = 0; kf < 4; ++kf) {
        const float* ap = arow + kf * 32 + l4 * 8;
        float4 v0 = *reinterpret_cast<const float4*>(ap);
        float4 v1 = *reinterpret_cast<const float4*>(ap + 4);
        float av[8] = {v0.x, v0.y, v0.z, v0.w, v1.x, v1.y, v1.z, v1.w};
        u32 hp[4], lp[4];
#pragma unroll
        for (int p = 0; p < 4; ++p) {
            float a0 = av[2 * p], a1 = av[2 * p + 1];
            u32 h0 = __float_as_uint(a0) & 0xFFFF0000u;
            u32 h1 = __float_as_uint(a1) & 0xFFFF0000u;
            float q0 = a0 - __uint_as_float(h0);
            float q1 = a1 - __uint_as_float(h1);
            hp[p] = (h0 >> 16) | h1;
            lp[p] = ((__float_as_uint(q0) & 0xFFFF0000u) >> 16) |
                    (__float_as_uint(q1) & 0xFFFF0000u);
        }
        ahi[kf] = pack_bf16x8(hp[0], hp[1], hp[2], hp[3]);
        alo[kf] = pack_bf16x8(lp[0], lp[1], lp[2], lp[3]);
    }

    f32x4 accQ[8] = {};

    stage_sec(ftabW1);   // W1 half 0
    __syncthreads();

    for (int half = 0; half < NHALF; ++half) {
        // ---------------- phase 1: accH = W1h^T · A^T ----------------
        f32x4 accH[8] = {};
#pragma unroll
        for (int kf = 0; kf < 4; ++kf) {
            uint4 wh[8];
#pragma unroll
            for (int nf = 0; nf < 8; ++nf)
                wh[nf] = *reinterpret_cast<const uint4*>(
                    lds_w + (kf * 8 + nf) * 256 + 4 * l);
            __builtin_amdgcn_sched_group_barrier(0x100, 8, 0);   // 8 DS_READ
#pragma unroll
            for (int nf = 0; nf < 8; ++nf) {
                bf16x8 whi = as_bf16x8(wh[nf]);
                accH[nf] = __builtin_amdgcn_mfma_f32_16x16x32_bf16(whi, ahi[kf], accH[nf], 0, 0, 0);
                accH[nf] = __builtin_amdgcn_mfma_f32_16x16x32_bf16(whi, alo[kf], accH[nf], 0, 0, 0);
            }
            __builtin_amdgcn_sched_group_barrier(0x8, 16, 0);    // 16 MFMA
        }
        __syncthreads();                           // done reading W1h
        stage_sec(ftabW2 + (size_t)half * 8192);   // async stage W2h

        // ---- epilogue 1 (VALU, overlaps staging): bias+act, split-pack ----
        u32 hpk[8][4];
#pragma unroll
        for (int nf = 0; nf < 8; ++nf) {
            const float4 bb = *reinterpret_cast<const float4*>(
                b1v + half * 128 + nf * 16 + l4 * 4);
            const float bbv[4] = {bb.x, bb.y, bb.z, bb.w};
#pragma unroll
            for (int reg = 0; reg < 4; ++reg) {
                float v = accH[nf][reg] + bbv[reg];
                if (ACT1 == 1) v = fmaxf(v, 0.0f);
                else           v = v > 0.0f ? v : (expf(v) - 1.0f);
                u32 vh = __float_as_uint(v) & 0xFFFF0000u;
                float rr = v - __uint_as_float(vh);
                hpk[nf][reg] = (vh >> 16) | (__float_as_uint(rr) & 0xFFFF0000u);
            }
        }
        __syncthreads();                           // W2h staged & visible

        // ---------------- phase 2: accQ += W2h^T · H^T ----------------
#pragma unroll
        for (int kf = 0; kf < 4; ++kf) {
            uint4 wh[8];
#pragma unroll
            for (int nf = 0; nf < 8; ++nf)
                wh[nf] = *reinterpret_cast<const uint4*>(
                    lds_w + (kf * 8 + nf) * 256 + 4 * l);
            __builtin_amdgcn_sched_group_barrier(0x100, 8, 0);   // 8 DS_READ

            u32 got[8];
#pragma unroll
            for (int je = 0; je < 8; ++je) {
                int srcLane = ((l4 & 1) * 2 + (je >> 2)) * 16 + l15;
                u32 g0 = __shfl(hpk[2 * kf][je & 3], srcLane, 64);
                u32 g1 = __shfl(hpk[2 * kf + 1][je & 3], srcLane, 64);
                got[je] = (l4 & 2) ? g1 : g0;
            }
            u32 hh[4], gg[4];
#pragma unroll
            for (int p = 0; p < 4; ++p) {
                hh[p] = (got[2 * p] & 0xFFFFu) | (got[2 * p + 1] << 16);
                gg[p] = (got[2 * p] >> 16) | (got[2 * p + 1] & 0xFFFF0000u);
            }
            bf16x8 bh = pack_bf16x8(hh[0], hh[1], hh[2], hh[3]);
            bf16x8 bl = pack_bf16x8(gg[0], gg[1], gg[2], gg[3]);

#pragma unroll
            for (int nf = 0; nf < 8; ++nf) {
                bf16x8 whi = as_bf16x8(wh[nf]);
                accQ[nf] = __builtin_amdgcn_mfma_f32_16x16x32_bf16(whi, bh, accQ[nf], 0, 0, 0);
                accQ[nf] = __builtin_amdgcn_mfma_f32_16x16x32_bf16(whi, bl, accQ[nf], 0, 0, 0);
            }
            __builtin_amdgcn_sched_group_barrier(0x8, 16, 0);    // 16 MFMA
        }

        if (half + 1 < NHALF) {
            __syncthreads();
            stage_sec(ftabW1 + (size_t)(half + 1) * 8192);
            __syncthreads();
        }
    }

    // ---- final epilogue ----
    if (r < M) {
        if (BF16_OUT) {
            float sc = dscale[r];
#pragma unroll
            for (int nf = 0; nf < 8; ++nf) {
                u32 w0 = rne_bf16(accQ[nf][0] * sc) | (rne_bf16(accQ[nf][1] * sc) << 16);
                u32 w1 = rne_bf16(accQ[nf][2] * sc) | (rne_bf16(accQ[nf][3] * sc) << 16);
                reinterpret_cast<uint2*>(C16)[(size_t)r * 32 + nf * 4 + l4] =
                    make_uint2(w0, w1);
            }
        } else {
#pragma unroll
            for (int nf = 0; nf < 8; ++nf) {
                float4 v;
                v.x = accQ[nf][0]; v.y = accQ[nf][1];
                v.z = accQ[nf][2]; v.w = accQ[nf][3];
                if (FINAL_BIAS) {
                    const float4 bb = *reinterpret_cast<const float4*>(b2v + nf * 16 + l4 * 4);
                    v.x += bb.x; v.y += bb.y; v.z += bb.z; v.w += bb.w;
                }
                *reinterpret_cast<float4*>(C + (size_t)r * 128 + nf * 16 + l4 * 4) = v;
            }
        }
    }
}

// ---------------------------------------------------------------------------
// launch
// ---------------------------------------------------------------------------

extern "C" void kernel_launch(void* const* d_in, const int* in_sizes, int n_in,
                              void* d_out, int out_size, void* d_ws, size_t ws_size,
                              hipStream_t stream) {
    const float* x    = (const float*)d_in[0];
    const int*   ei   = (const int*)d_in[1];   // int64 in reference -> int32 from harness
    const float* W1   = (const float*)d_in[2]; // [128,256]
    const float* b1   = (const float*)d_in[3];
    const float* W2   = (const float*)d_in[4]; // [256,128]
    const float* b2   = (const float*)d_in[5];
    const float* fcW1 = (const float*)d_in[6]; // [128,128]
    const float* fcb1 = (const float*)d_in[7];
    const float* fcW2 = (const float*)d_in[8]; // [128,128]
    const float* fcb2 = (const float*)d_in[9];
    float* out        = (float*)d_out;         // [N,128], also ping-pong scratch

    char* ws = (char*)d_ws;
    size_t off = 0;
    auto alloc = [&](size_t bytes) {
        void* p = ws + off;
        off += (bytes + 255) & ~(size_t)255;
        return p;
    };
    int*   counts  = (int*)alloc(N_NODES * sizeof(int));
    int*   cursor  = (int*)alloc(N_NODES * sizeof(int));
    int*   part    = (int*)alloc(N_NODES * sizeof(int));
    int*   bsum    = (int*)alloc(SCAN_BLOCKS * sizeof(int));
    int*   boff    = (int*)alloc(SCAN_BLOCKS * sizeof(int));
    int*   offsets = (int*)alloc((N_NODES + 1) * sizeof(int));
    u16*   csr     = (u16*)alloc(N_EDGES * sizeof(u16));
    float* dinv    = (float*)alloc(N_NODES * sizeof(float));
    u32*   ftab    = (u32*)alloc((size_t)6 * 8192 * sizeof(u32));
    u32*   xs      = (u32*)alloc((size_t)N_NODES * 128 * 2);   // bf16 features
    u32*   qs      = (u32*)alloc((size_t)N_NODES * 128 * 2);   // bf16 mid output
    (void)ws_size; (void)n_in; (void)in_sizes; (void)out_size;

    const u32 SEC = 8192;  // u32 per 32 KB section

    // graph preprocessing + weight prep
    k_init<<<SCAN_BLOCKS + 192, 256, 0, stream>>>(counts, W1, W2, fcW1, fcW2, ftab);
    k_count<<<(N_EDGES / 4 + 255) / 256, 256, 0, stream>>>(ei, counts);
    k_scan1<<<SCAN_BLOCKS, 256, 0, stream>>>(counts, part, bsum);
    k_scan2<<<1, 256, 0, stream>>>(bsum, boff);
    k_scan3<<<SCAN_BLOCKS, 256, 0, stream>>>(part, counts, boff, offsets, cursor, dinv);
    k_xscale<<<(N_NODES * 32 + 255) / 256, 256, 0, stream>>>(x, dinv, xs);
    k_fill<<<(N_EDGES + 255) / 256, 256, 0, stream>>>(ei, cursor, csr);

    const int prop_grid = (N_NODES + 7) / 8;  // 6250: 8 nodes/block, 2 per wave
    const int gm = (N_NODES + 63) / 64;       // 782 (64 rows/block, 16 per wave)

    // layer 1 propagate: agg = dinv*(sum xs + xs_self) -> out (f32 scratch)
    k_prop<false, false><<<prop_grid, 256, 0, stream>>>(xs, out, dinv, offsets, csr, nullptr);

    // fused mid: qs = bf16( dinv * (relu(agg@W1 + b1) @ W2) )
    k_fused<2, 1, false, true><<<gm, 256, 0, stream>>>(out, ftab, ftab + 2 * SEC,
                                                       b1, nullptr, nullptr, qs, dinv, N_NODES);

    // layer 2 propagate: z = relu( dinv*(sum qs + qs_self) + b2 ) -> out
    k_prop<true, true><<<prop_grid, 256, 0, stream>>>(qs, out, dinv, offsets, csr, b2);

    // fused head (in-place): out = elu(out@fcW1 + fcb1) @ fcW2 + fcb2
    k_fused<1, 2, true, false><<<gm, 256, 0, stream>>>(out, ftab + 4 * SEC, ftab + 5 * SEC,
                                                       fcb1, fcb2, out, nullptr, nullptr, N_NODES);
}

// Round 23
// 211.431 us; speedup vs baseline: 1.0647x; 1.0193x over previous
//
#include <hip/hip_runtime.h>
#include <hip/hip_bf16.h>
#include <cstdint>

#define N_NODES 50000
#define N_EDGES 800000
#define SCAN_BLOCKS ((N_NODES + 255) / 256)   // 196
#define XF_BLOCKS 9375                         // 3 * 3125: 2/3 xscale, 1/3 fill

typedef __attribute__((ext_vector_type(8))) short bf16x8;
typedef __attribute__((ext_vector_type(4))) float f32x4;
typedef unsigned int u32;
typedef unsigned short u16;

__device__ __forceinline__ bf16x8 pack_bf16x8(u32 a, u32 b, u32 c, u32 d) {
    union { u32 u[4]; bf16x8 v; } x;
    x.u[0] = a; x.u[1] = b; x.u[2] = c; x.u[3] = d;
    return x.v;
}

__device__ __forceinline__ bf16x8 as_bf16x8(uint4 v) {
    union { uint4 u; bf16x8 b; } x;
    x.u = v;
    return x.b;
}

__device__ __forceinline__ u32 rne_bf16(float x) {
    u32 u = __float_as_uint(x);
    return (u + 0x7FFFu + ((u >> 16) & 1u)) >> 16;
}

// async global->LDS, 16B per lane: lds dest = base + lane*16, g is per-lane.
__device__ __forceinline__ void stage16(const u32* g, u32* lds) {
    __builtin_amdgcn_global_load_lds(
        (const __attribute__((address_space(1))) u32*)g,
        (__attribute__((address_space(3))) u32*)lds, 16, 0, 0);
}

__device__ __forceinline__ int clamp_node(int v) {
    return v < 0 ? 0 : (v >= N_NODES ? N_NODES - 1 : v);
}

// ---------------------------------------------------------------------------
// k_init: blocks [0,196) zero counts; blocks [196,388) do weight prep.
// Weight prep: SINGLE RNE-bf16 fragments; section = 32 KB = 8192 u32;
// frag f = kf*8+nf at section*8192 + f*256; lane l's uint4 at +4l.
// Lane l holds W[k=kf*32+(l>>4)*8+j][n=nf*16+(l&15)].
// Sections: 0,1 = W1 N-halves; 2,3 = W2 K-halves; 4 = fcW1; 5 = fcW2.
// ---------------------------------------------------------------------------

__global__ __launch_bounds__(256) void k_init(int* __restrict__ counts,
                                              const float* __restrict__ W1,
                                              const float* __restrict__ W2,
                                              const float* __restrict__ fcW1,
                                              const float* __restrict__ fcW2,
                                              u32* __restrict__ ftab) {
    if (blockIdx.x < SCAN_BLOCKS) {
        int i = blockIdx.x * 256 + threadIdx.x;
        if (i < N_NODES) counts[i] = 0;
        return;
    }
    int bx = blockIdx.x - SCAN_BLOCKS;    // 0..191
    int l = threadIdx.x;
    if (l >= 64) return;
    int s = bx >> 5, f = bx & 31;
    int kf = f >> 3, nf = f & 7;
    const float* src; int ld, roff, coff;
    switch (s) {
        case 0:  src = W1;   ld = 256; roff = 0;   coff = 0;   break;
        case 1:  src = W1;   ld = 256; roff = 0;   coff = 128; break;
        case 2:  src = W2;   ld = 128; roff = 0;   coff = 0;   break;
        case 3:  src = W2;   ld = 128; roff = 128; coff = 0;   break;
        case 4:  src = fcW1; ld = 128; roff = 0;   coff = 0;   break;
        default: src = fcW2; ld = 128; roff = 0;   coff = 0;   break;
    }
    int col = coff + nf * 16 + (l & 15);
    int krow = roff + kf * 32 + (l >> 4) * 8;
    u32 hp[4];
#pragma unroll
    for (int p = 0; p < 4; ++p) {
        float a0 = src[(size_t)(krow + 2 * p) * ld + col];
        float a1 = src[(size_t)(krow + 2 * p + 1) * ld + col];
        hp[p] = rne_bf16(a0) | (rne_bf16(a1) << 16);
    }
    u32* dst = ftab + (size_t)s * 8192 + (size_t)f * 256;
    *reinterpret_cast<uint4*>(dst + 4 * l) = make_uint4(hp[0], hp[1], hp[2], hp[3]);
}

// 4 edges per thread (uint4 dst load; N_EDGES % 4 == 0)
__global__ void k_count(const int* __restrict__ ei, int* __restrict__ counts) {
    int t = blockIdx.x * blockDim.x + threadIdx.x;
    if (t < N_EDGES / 4) {
        int4 d = reinterpret_cast<const int4*>(ei + N_EDGES)[t];
        atomicAdd(&counts[clamp_node(d.x)], 1);
        atomicAdd(&counts[clamp_node(d.y)], 1);
        atomicAdd(&counts[clamp_node(d.z)], 1);
        atomicAdd(&counts[clamp_node(d.w)], 1);
    }
}

__global__ __launch_bounds__(256) void k_scan1(const int* __restrict__ counts,
                                               int* __restrict__ part,
                                               int* __restrict__ bsum) {
    __shared__ int s[256];
    const int tid = threadIdx.x;
    const int i = blockIdx.x * 256 + tid;
    int v = (i < N_NODES) ? counts[i] : 0;
    s[tid] = v;
    __syncthreads();
    for (int off = 1; off < 256; off <<= 1) {
        int t = (tid >= off) ? s[tid - off] : 0;
        __syncthreads();
        s[tid] += t;
        __syncthreads();
    }
    if (i < N_NODES) part[i] = s[tid];
    if (tid == 255) bsum[blockIdx.x] = s[255];
}

// scan3 now also performs the block-sum scan internally (replaces k_scan2),
// and emits offsets, cursor (copy) and dinv.
__global__ __launch_bounds__(256) void k_scan3(const int* __restrict__ part,
                                               const int* __restrict__ counts,
                                               const int* __restrict__ bsum,
                                               int* __restrict__ offsets,
                                               int* __restrict__ cursor,
                                               float* __restrict__ dinv) {
    __shared__ int s[256];
    __shared__ int myboff;
    const int tid = threadIdx.x;
    int v = (tid < SCAN_BLOCKS) ? bsum[tid] : 0;
    s[tid] = v;
    __syncthreads();
    for (int off = 1; off < 256; off <<= 1) {
        int t = (tid >= off) ? s[tid - off] : 0;
        __syncthreads();
        s[tid] += t;
        __syncthreads();
    }
    if (tid == 0) myboff = (blockIdx.x == 0) ? 0 : s[blockIdx.x - 1];
    __syncthreads();

    const int i = blockIdx.x * 256 + tid;
    if (i < N_NODES) {
        int off = part[i] - counts[i] + myboff;
        offsets[i] = off;
        cursor[i]  = off;
        dinv[i]    = rsqrtf((float)counts[i] + 1.0f);
    }
    if (i == 0) offsets[N_NODES] = N_EDGES;
}

// ---------------------------------------------------------------------------
// k_xf: ROUND-ROBIN interleave of xscale (2/3 of blocks) and fill (1/3),
// so both phases start together and co-schedule (r21's phase-ordered merge
// serialized; this fixes the dispatch-order mechanism).
// ---------------------------------------------------------------------------

__global__ __launch_bounds__(256) void k_xf(const float* __restrict__ x,
                                            const float* __restrict__ dinv,
                                            u32* __restrict__ xs,
                                            const int* __restrict__ ei,
                                            int* __restrict__ cursor,
                                            u16* __restrict__ csr) {
    const int grp = blockIdx.x / 3;
    const int rem = blockIdx.x % 3;
    if (rem == 2) {
        // fill block grp (0..3124)
        int e = grp * 256 + threadIdx.x;
        if (e < N_EDGES) {
            int src = clamp_node(ei[e]);
            int dst = clamp_node(ei[N_EDGES + e]);
            int slot = atomicAdd(&cursor[dst], 1);
            if (slot >= 0 && slot < N_EDGES) csr[slot] = (u16)src;
        }
    } else {
        // xscale block grp*2+rem (0..6249)
        int idx = (grp * 2 + rem) * 256 + threadIdx.x;
        if (idx < N_NODES * 32) {
            int node = idx >> 5;
            float di = dinv[node];
            float4 v = reinterpret_cast<const float4*>(x)[idx];
            u32 w0 = rne_bf16(v.x * di) | (rne_bf16(v.y * di) << 16);
            u32 w1 = rne_bf16(v.z * di) | (rne_bf16(v.w * di) << 16);
            reinterpret_cast<uint2*>(xs)[idx] = make_uint2(w0, w1);
        }
    }
}

// ---------------------------------------------------------------------------
// Propagation over pre-scaled bf16 features; csr u16; plain f32 stores.
// ---------------------------------------------------------------------------

template <bool HAS_BIAS, bool RELU>
__global__ __launch_bounds__(256) void k_prop(const u32* __restrict__ xs,
                                              float* __restrict__ out,
                                              const float* __restrict__ dinv,
                                              const int* __restrict__ offsets,
                                              const u16* __restrict__ csr,
                                              const float* __restrict__ bias) {
    const int wave = threadIdx.x >> 6;
    const int lane = threadIdx.x & 63;
    const int half = lane >> 5;
    const int lc   = lane & 31;          // 4-channel group
    const int node = (blockIdx.x * 4 + wave) * 2 + half;
    if (node >= N_NODES) return;

    const uint2* __restrict__ xp = reinterpret_cast<const uint2*>(xs);
    const float di = dinv[node];

    uint2 sv = xp[(size_t)node * 32 + lc];
    float ax = __uint_as_float(sv.x << 16);
    float ay = __uint_as_float(sv.x & 0xFFFF0000u);
    float az = __uint_as_float(sv.y << 16);
    float aw = __uint_as_float(sv.y & 0xFFFF0000u);

    int e = offsets[node];
    const int eend = offsets[node + 1];
    for (; e + 4 <= eend; e += 4) {
        int s0 = csr[e + 0], s1 = csr[e + 1], s2 = csr[e + 2], s3 = csr[e + 3];
        uint2 v0 = xp[(size_t)s0 * 32 + lc];
        uint2 v1 = xp[(size_t)s1 * 32 + lc];
        uint2 v2 = xp[(size_t)s2 * 32 + lc];
        uint2 v3 = xp[(size_t)s3 * 32 + lc];
        ax += __uint_as_float(v0.x << 16);
        ay += __uint_as_float(v0.x & 0xFFFF0000u);
        az += __uint_as_float(v0.y << 16);
        aw += __uint_as_float(v0.y & 0xFFFF0000u);
        ax += __uint_as_float(v1.x << 16);
        ay += __uint_as_float(v1.x & 0xFFFF0000u);
        az += __uint_as_float(v1.y << 16);
        aw += __uint_as_float(v1.y & 0xFFFF0000u);
        ax += __uint_as_float(v2.x << 16);
        ay += __uint_as_float(v2.x & 0xFFFF0000u);
        az += __uint_as_float(v2.y << 16);
        aw += __uint_as_float(v2.y & 0xFFFF0000u);
        ax += __uint_as_float(v3.x << 16);
        ay += __uint_as_float(v3.x & 0xFFFF0000u);
        az += __uint_as_float(v3.y << 16);
        aw += __uint_as_float(v3.y & 0xFFFF0000u);
    }
    for (; e < eend; ++e) {
        int s = csr[e];
        uint2 v = xp[(size_t)s * 32 + lc];
        ax += __uint_as_float(v.x << 16);
        ay += __uint_as_float(v.x & 0xFFFF0000u);
        az += __uint_as_float(v.y << 16);
        aw += __uint_as_float(v.y & 0xFFFF0000u);
    }

    float4 o;
    o.x = di * ax; o.y = di * ay; o.z = di * az; o.w = di * aw;
    if (HAS_BIAS) {
        float4 bb = reinterpret_cast<const float4*>(bias)[lc];
        o.x += bb.x; o.y += bb.y; o.z += bb.z; o.w += bb.w;
    }
    if (RELU) {
        o.x = fmaxf(o.x, 0.0f); o.y = fmaxf(o.y, 0.0f);
        o.z = fmaxf(o.z, 0.0f); o.w = fmaxf(o.w, 0.0f);
    }
    reinterpret_cast<float4*>(out)[(size_t)node * 32 + lc] = o;
}

// ---------------------------------------------------------------------------
// Fused 2-GEMM chain, 2-PRODUCT scheme (r17/r20/r22): W is RNE-bf16 (single
// frag), A split hi/lo so w*ahi + w*alo = w*a exactly. 32 KB section
// LDS-resident per phase, pure-LDS inner loops, 64-row blocks, grid 782.
// ---------------------------------------------------------------------------

template <int NHALF, int ACT1, bool FINAL_BIAS, bool BF16_OUT>
__global__ __launch_bounds__(256, 3) void k_fused(
        const float* __restrict__ A,
        const u32* __restrict__ ftabW1,
        const u32* __restrict__ ftabW2,
        const float* __restrict__ b1v,
        const float* __restrict__ b2v,
        float* __restrict__ C,
        u32* __restrict__ C16,
        const float* __restrict__ dscale,
        int M) {
    __shared__ u32 lds_w[8192];   // 32 KB: one phase's weight section

    const int tid = threadIdx.x;
    const int wave = tid >> 6, l = tid & 63;
    const int l15 = l & 15, l4 = l >> 4;
    const int r = blockIdx.x * 64 + wave * 16 + l15;
    const float* arow = A + (size_t)(r < M ? r : M - 1) * 128;

    auto stage_sec = [&](const u32* sec) {
#pragma unroll
        for (int i = 0; i < 8; ++i) {
            int off = (i * 4 + wave) * 256;
            stage16(sec + off + 4 * l, lds_w + off);
        }
    };

    // A fragments loaded/split ONCE
    bf16x8 ahi[4], alo[4];
#pragma unroll
    for (int kf = 0; kf < 4; ++kf) {
        const float* ap = arow + kf * 32 + l4 * 8;
        float4 v0 = *reinterpret_cast<const float4*>(ap);
        float4 v1 = *reinterpret_cast<const float4*>(ap + 4);
        float av[8] = {v0.x, v0.y, v0.z, v0.w, v1.x, v1.y, v1.z, v1.w};
        u32 hp[4], lp[4];
#pragma unroll
        for (int p = 0; p < 4; ++p) {
            float a0 = av[2 * p], a1 = av[2 * p + 1];
            u32 h0 = __float_as_uint(a0) & 0xFFFF0000u;
            u32 h1 = __float_as_uint(a1) & 0xFFFF0000u;
            float q0 = a0 - __uint_as_float(h0);
            float q1 = a1 - __uint_as_float(h1);
            hp[p] = (h0 >> 16) | h1;
            lp[p] = ((__float_as_uint(q0) & 0xFFFF0000u) >> 16) |
                    (__float_as_uint(q1) & 0xFFFF0000u);
        }
        ahi[kf] = pack_bf16x8(hp[0], hp[1], hp[2], hp[3]);
        alo[kf] = pack_bf16x8(lp[0], lp[1], lp[2], lp[3]);
    }

    f32x4 accQ[8] = {};

    stage_sec(ftabW1);   // W1 half 0
    __syncthreads();

    for (int half = 0; half < NHALF; ++half) {
        // ---------------- phase 1: accH = W1h^T · A^T ----------------
        f32x4 accH[8] = {};
#pragma unroll
        for (int kf = 0; kf < 4; ++kf) {
            uint4 wh[8];
#pragma unroll
            for (int nf = 0; nf < 8; ++nf)
                wh[nf] = *reinterpret_cast<const uint4*>(
                    lds_w + (kf * 8 + nf) * 256 + 4 * l);
            __builtin_amdgcn_sched_group_barrier(0x100, 8, 0);   // 8 DS_READ
#pragma unroll
            for (int nf = 0; nf < 8; ++nf) {
                bf16x8 whi = as_bf16x8(wh[nf]);
                accH[nf] = __builtin_amdgcn_mfma_f32_16x16x32_bf16(whi, ahi[kf], accH[nf], 0, 0, 0);
                accH[nf] = __builtin_amdgcn_mfma_f32_16x16x32_bf16(whi, alo[kf], accH[nf], 0, 0, 0);
            }
            __builtin_amdgcn_sched_group_barrier(0x8, 16, 0);    // 16 MFMA
        }
        __syncthreads();                           // done reading W1h
        stage_sec(ftabW2 + (size_t)half * 8192);   // async stage W2h

        // ---- epilogue 1 (VALU, overlaps staging): bias+act, split-pack ----
        u32 hpk[8][4];
#pragma unroll
        for (int nf = 0; nf < 8; ++nf) {
            const float4 bb = *reinterpret_cast<const float4*>(
                b1v + half * 128 + nf * 16 + l4 * 4);
            const float bbv[4] = {bb.x, bb.y, bb.z, bb.w};
#pragma unroll
            for (int reg = 0; reg < 4; ++reg) {
                float v = accH[nf][reg] + bbv[reg];
                if (ACT1 == 1) v = fmaxf(v, 0.0f);
                else           v = v > 0.0f ? v : (expf(v) - 1.0f);
                u32 vh = __float_as_uint(v) & 0xFFFF0000u;
                float rr = v - __uint_as_float(vh);
                hpk[nf][reg] = (vh >> 16) | (__float_as_uint(rr) & 0xFFFF0000u);
            }
        }
        __syncthreads();                           // W2h staged & visible

        // ---------------- phase 2: accQ += W2h^T · H^T ----------------
#pragma unroll
        for (int kf = 0; kf < 4; ++kf) {
            uint4 wh[8];
#pragma unroll
            for (int nf = 0; nf < 8; ++nf)
                wh[nf] = *reinterpret_cast<const uint4*>(
                    lds_w + (kf * 8 + nf) * 256 + 4 * l);
            __builtin_amdgcn_sched_group_barrier(0x100, 8, 0);   // 8 DS_READ

            u32 got[8];
#pragma unroll
            for (int je = 0; je < 8; ++je) {
                int srcLane = ((l4 & 1) * 2 + (je >> 2)) * 16 + l15;
                u32 g0 = __shfl(hpk[2 * kf][je & 3], srcLane, 64);
                u32 g1 = __shfl(hpk[2 * kf + 1][je & 3], srcLane, 64);
                got[je] = (l4 & 2) ? g1 : g0;
            }
            u32 hh[4], gg[4];
#pragma unroll
            for (int p = 0; p < 4; ++p) {
                hh[p] = (got[2 * p] & 0xFFFFu) | (got[2 * p + 1] << 16);
                gg[p] = (got[2 * p] >> 16) | (got[2 * p + 1] & 0xFFFF0000u);
            }
            bf16x8 bh = pack_bf16x8(hh[0], hh[1], hh[2], hh[3]);
            bf16x8 bl = pack_bf16x8(gg[0], gg[1], gg[2], gg[3]);

#pragma unroll
            for (int nf = 0; nf < 8; ++nf) {
                bf16x8 whi = as_bf16x8(wh[nf]);
                accQ[nf] = __builtin_amdgcn_mfma_f32_16x16x32_bf16(whi, bh, accQ[nf], 0, 0, 0);
                accQ[nf] = __builtin_amdgcn_mfma_f32_16x16x32_bf16(whi, bl, accQ[nf], 0, 0, 0);
            }
            __builtin_amdgcn_sched_group_barrier(0x8, 16, 0);    // 16 MFMA
        }

        if (half + 1 < NHALF) {
            __syncthreads();
            stage_sec(ftabW1 + (size_t)(half + 1) * 8192);
            __syncthreads();
        }
    }

    // ---- final epilogue ----
    if (r < M) {
        if (BF16_OUT) {
            float sc = dscale[r];
#pragma unroll
            for (int nf = 0; nf < 8; ++nf) {
                u32 w0 = rne_bf16(accQ[nf][0] * sc) | (rne_bf16(accQ[nf][1] * sc) << 16);
                u32 w1 = rne_bf16(accQ[nf][2] * sc) | (rne_bf16(accQ[nf][3] * sc) << 16);
                reinterpret_cast<uint2*>(C16)[(size_t)r * 32 + nf * 4 + l4] =
                    make_uint2(w0, w1);
            }
        } else {
#pragma unroll
            for (int nf = 0; nf < 8; ++nf) {
                float4 v;
                v.x = accQ[nf][0]; v.y = accQ[nf][1];
                v.z = accQ[nf][2]; v.w = accQ[nf][3];
                if (FINAL_BIAS) {
                    const float4 bb = *reinterpret_cast<const float4*>(b2v + nf * 16 + l4 * 4);
                    v.x += bb.x; v.y += bb.y; v.z += bb.z; v.w += bb.w;
                }
                *reinterpret_cast<float4*>(C + (size_t)r * 128 + nf * 16 + l4 * 4) = v;
            }
        }
    }
}

// ---------------------------------------------------------------------------
// launch
// ---------------------------------------------------------------------------

extern "C" void kernel_launch(void* const* d_in, const int* in_sizes, int n_in,
                              void* d_out, int out_size, void* d_ws, size_t ws_size,
                              hipStream_t stream) {
    const float* x    = (const float*)d_in[0];
    const int*   ei   = (const int*)d_in[1];   // int64 in reference -> int32 from harness
    const float* W1   = (const float*)d_in[2]; // [128,256]
    const float* b1   = (const float*)d_in[3];
    const float* W2   = (const float*)d_in[4]; // [256,128]
    const float* b2   = (const float*)d_in[5];
    const float* fcW1 = (const float*)d_in[6]; // [128,128]
    const float* fcb1 = (const float*)d_in[7];
    const float* fcW2 = (const float*)d_in[8]; // [128,128]
    const float* fcb2 = (const float*)d_in[9];
    float* out        = (float*)d_out;         // [N,128], also ping-pong scratch

    char* ws = (char*)d_ws;
    size_t off = 0;
    auto alloc = [&](size_t bytes) {
        void* p = ws + off;
        off += (bytes + 255) & ~(size_t)255;
        return p;
    };
    int*   counts  = (int*)alloc(N_NODES * sizeof(int));
    int*   cursor  = (int*)alloc(N_NODES * sizeof(int));
    int*   part    = (int*)alloc(N_NODES * sizeof(int));
    int*   bsum    = (int*)alloc(SCAN_BLOCKS * sizeof(int));
    int*   offsets = (int*)alloc((N_NODES + 1) * sizeof(int));
    u16*   csr     = (u16*)alloc(N_EDGES * sizeof(u16));
    float* dinv    = (float*)alloc(N_NODES * sizeof(float));
    u32*   ftab    = (u32*)alloc((size_t)6 * 8192 * sizeof(u32));
    u32*   xs      = (u32*)alloc((size_t)N_NODES * 128 * 2);   // bf16 features
    u32*   qs      = (u32*)alloc((size_t)N_NODES * 128 * 2);   // bf16 mid output
    (void)ws_size; (void)n_in; (void)in_sizes; (void)out_size;

    const u32 SEC = 8192;  // u32 per 32 KB section

    // graph preprocessing + weight prep
    k_init<<<SCAN_BLOCKS + 192, 256, 0, stream>>>(counts, W1, W2, fcW1, fcW2, ftab);
    k_count<<<(N_EDGES / 4 + 255) / 256, 256, 0, stream>>>(ei, counts);
    k_scan1<<<SCAN_BLOCKS, 256, 0, stream>>>(counts, part, bsum);
    k_scan3<<<SCAN_BLOCKS, 256, 0, stream>>>(part, counts, bsum, offsets, cursor, dinv);
    k_xf<<<XF_BLOCKS, 256, 0, stream>>>(x, dinv, xs, ei, cursor, csr);

    const int prop_grid = (N_NODES + 7) / 8;  // 6250: 8 nodes/block, 2 per wave
    const int gm = (N_NODES + 63) / 64;       // 782 (64 rows/block, 16 per wave)

    // layer 1 propagate: agg = dinv*(sum xs + xs_self) -> out (f32 scratch)
    k_prop<false, false><<<prop_grid, 256, 0, stream>>>(xs, out, dinv, offsets, csr, nullptr);

    // fused mid: qs = bf16( dinv * (relu(agg@W1 + b1) @ W2) )
    k_fused<2, 1, false, true><<<gm, 256, 0, stream>>>(out, ftab, ftab + 2 * SEC,
                                                       b1, nullptr, nullptr, qs, dinv, N_NODES);

    // layer 2 propagate: z = relu( dinv*(sum qs + qs_self) + b2 ) -> out
    k_prop<true, true><<<prop_grid, 256, 0, stream>>>(qs, out, dinv, offsets, csr, b2);

    // fused head (in-place): out = elu(out@fcW1 + fcb1) @ fcW2 + fcb2
    k_fused<1, 2, true, false><<<gm, 256, 0, stream>>>(out, ftab + 4 * SEC, ftab + 5 * SEC,
                                                       fcb1, fcb2, out, nullptr, nullptr, N_NODES);
}